// Round 12
// baseline (72.745 us; speedup 1.0000x reference)
//
#include <hip/hip_runtime.h>

#define A_TOTAL 34000

// 267 tiles x 16 batches, 128-thr blocks (v11 decomposition, best measured).
// Walk rewritten as TWO passes to kill the loop-carried f64 filter chain that
// v10's counters (VALUBusy 10.8%) exposed as the stall source:
//   pass 1: branch-free approx scan — rcp-based iou, fmax carry (2 cyc),
//           candidate bitmask with provable 1e-6 slack. Pipelines fully.
//   pass 2: exact rn-chain + __fdiv_rn re-eval of the few candidates, strict
//           first-max in ascending index order == np.argmax bit-exactly.

__global__ __launch_bounds__(128) void multi_anchor_encode_v12(
    const float* __restrict__ boxes,   // [B, 128, 4] yxyx f32
    float* __restrict__ out)           // [B, A_TOTAL, 5] f32
{
    __shared__ float4 cbox[128];   // compacted survivors, ascending box order
    __shared__ float  csum[128];   // area_a + area_box (pre-added, rn)
    __shared__ int    scnt;

    const int b    = blockIdx.y;
    const int t    = threadIdx.x;      // 0..127
    const int bid  = blockIdx.x;
    const int w    = t >> 6;           // wave 0 | 1
    const int lane = t & 63;

    // ---- Anchor decode + block-uniform conservative tile bounds ----
    int   ia = 0, ja = 0, a_flat = 0;
    float s = 4.f, asize = 16.f;
    bool  valid = true;
    float ty0, ty1, tx0, tx1;

    if (bid < 200) {                       // L0: 16 cols x 8 rows
        int ty = bid / 10, tx = bid - ty * 10;       // ty 0..19, tx 0..9
        int i0 = ty * 8, j0 = tx * 16;
        ia = i0 + (t >> 4); ja = j0 + (t & 15);
        s = 4.f; asize = 16.f;
        a_flat = ia * 160 + ja;
        ty0 = (float)(i0 * 4 - 8);  ty1 = (float)((i0 + 7) * 4 + 8);
        tx0 = (float)(j0 * 4 - 8);  tx1 = (float)((j0 + 15) * 4 + 8);
    } else if (bid < 250) {                // L1: 16 cols x 8 rows
        int q = bid - 200; int ty = q / 5, tx = q - ty * 5;
        int i0 = ty * 8, j0 = tx * 16;
        ia = i0 + (t >> 4); ja = j0 + (t & 15);
        s = 8.f; asize = 32.f;
        a_flat = 25600 + ia * 80 + ja;
        ty0 = (float)(i0 * 8 - 16); ty1 = (float)((i0 + 7) * 8 + 16);
        tx0 = (float)(j0 * 8 - 16); tx1 = (float)((j0 + 15) * 8 + 16);
    } else if (bid < 263) {                // L2: flat chunks of 128 (y-band)
        int c = bid - 250; int k = c * 128 + t;
        valid = (k < 1600); int kk = valid ? k : 0;
        ia = kk / 40; ja = kk - ia * 40;
        s = 16.f; asize = 64.f;
        a_flat = 32000 + kk;
        int klo = c * 128, khi = (klo + 127 < 1599) ? klo + 127 : 1599;
        int ilo = klo / 40, ihi = khi / 40;
        ty0 = (float)(ilo * 16 - 32); ty1 = (float)(ihi * 16 + 32);
        tx0 = -1e30f; tx1 = 1e30f;
    } else {                               // L3: flat chunks of 128 (y-band)
        int c = bid - 263; int k = c * 128 + t;
        valid = (k < 400); int kk = valid ? k : 0;
        ia = kk / 20; ja = kk - ia * 20;
        s = 32.f; asize = 128.f;
        a_flat = 33600 + kk;
        int klo = c * 128, khi = (klo + 127 < 399) ? klo + 127 : 399;
        int ilo = klo / 20, ihi = khi / 20;
        ty0 = (float)(ilo * 32 - 64); ty1 = (float)(ihi * 32 + 64);
        tx0 = -1e30f; tx1 = 1e30f;
    }

    const float area_a = asize * asize;    // exact (block-uniform)

    // ---- Staging (v11's proven scheme): both waves load + identical ballots;
    // wave 0 compacts boxes 0..63, wave 1 boxes 64..127; ONE barrier. ----
    const float4* bb = reinterpret_cast<const float4*>(boxes + (size_t)b * 128 * 4);
    {
        float4 vA = bb[lane];              // x=ymin y=xmin z=ymax w=xmax
        float4 vB = bb[lane + 64];
        bool kA = (vA.z >= ty0) && (vA.x <= ty1) && (vA.w >= tx0) && (vA.y <= tx1);
        bool kB = (vB.z >= ty0) && (vB.x <= ty1) && (vB.w >= tx0) && (vB.y <= tx1);
        unsigned long long mA = __ballot(kA);
        unsigned long long mB = __ballot(kB);
        unsigned long long below = (1ull << lane) - 1ull;
        if (w == 0) {
            if (kA) {
                int p = __popcll(mA & below);
                cbox[p] = vA;
                csum[p] = __fadd_rn(area_a,
                          __fmul_rn(__fsub_rn(vA.z, vA.x), __fsub_rn(vA.w, vA.y)));
            }
        } else {
            if (kB) {
                int p = __popcll(mA) + __popcll(mB & below);
                cbox[p] = vB;
                csum[p] = __fadd_rn(area_a,
                          __fmul_rn(__fsub_rn(vB.z, vB.x), __fsub_rn(vB.w, vB.y)));
            }
        }
        if (t == 0) scnt = __popcll(mA) + __popcll(mB);
    }
    __syncthreads();                       // the ONLY barrier

    const float half = asize * 0.5f;       // exact (power of two)
    const float cy = (float)ia * s, cx = (float)ja * s;  // exact ints in f32
    const float ay0 = cy - half, ax0 = cx - half;
    const float ay1 = cy + half, ax1 = cx + half;
    const float inv = 1.0f / asize;        // exact power of two

    const int cnt = scnt;                  // wave-uniform LDS broadcast

    // ---- PASS 1: branch-free approx scan. Loop-carry = fmax (2 cyc) and the
    // mask OR (parallel). rcp error <= ~2.5 ulp; candidate slack 1e-6 rel
    // provably contains the exact argmax and all exact ties (see analysis).
    float best_a = 0.0f;
    unsigned long long cm0 = 0ull, cm1 = 0ull;
    const int c64 = cnt < 64 ? cnt : 64;
    #pragma unroll 4
    for (int m = 0; m < c64; ++m) {
        float4 v  = cbox[m];
        float  su = csum[m];
        float ymin = fmaxf(ay0, v.x);
        float xmin = fmaxf(ax0, v.y);
        float ymax = fminf(ay1, v.z);
        float xmax = fminf(ax1, v.w);
        float ih   = fmaxf(__fsub_rn(ymax, ymin), 0.0f);
        float iw   = fmaxf(__fsub_rn(xmax, xmin), 0.0f);
        float inter = __fmul_rn(ih, iw);
        float denom = __fsub_rn(su, inter);
        float qa    = __fmul_rn(inter, __frcp_rn(denom));   // approx iou
        bool  cand  = qa > __fmul_rn(best_a, 0.999999f);    // qa==0 never cands
        cm0 |= cand ? (1ull << m) : 0ull;
        best_a = fmaxf(best_a, qa);
    }
    #pragma unroll 4
    for (int m = 64; m < cnt; ++m) {
        float4 v  = cbox[m];
        float  su = csum[m];
        float ymin = fmaxf(ay0, v.x);
        float xmin = fmaxf(ax0, v.y);
        float ymax = fminf(ay1, v.z);
        float xmax = fminf(ax1, v.w);
        float ih   = fmaxf(__fsub_rn(ymax, ymin), 0.0f);
        float iw   = fmaxf(__fsub_rn(xmax, xmin), 0.0f);
        float inter = __fmul_rn(ih, iw);
        float denom = __fsub_rn(su, inter);
        float qa    = __fmul_rn(inter, __frcp_rn(denom));
        bool  cand  = qa > __fmul_rn(best_a, 0.999999f);
        cm1 |= cand ? (1ull << (m - 64)) : 0ull;
        best_a = fmaxf(best_a, qa);
    }

    // ---- PASS 2: exact re-eval of candidates, ascending order -> first-max.
    // Accept path is the thrice-validated bit-exact numpy f32 chain.
    float best = 0.0f; int bl = -1;
    #pragma unroll 1
    for (int word = 0; word < 2; ++word) {
        unsigned long long cm = word ? cm1 : cm0;
        int jb = word << 6;
        while (cm) {
            int j = jb + (int)__builtin_ctzll(cm);
            cm &= cm - 1;
            float4 v  = cbox[j];
            float  su = csum[j];
            float ymin = fmaxf(ay0, v.x);
            float xmin = fmaxf(ax0, v.y);
            float ymax = fminf(ay1, v.z);
            float xmax = fminf(ax1, v.w);
            float ih   = fmaxf(__fsub_rn(ymax, ymin), 0.0f);
            float iw   = fmaxf(__fsub_rn(xmax, xmin), 0.0f);
            float inter = __fmul_rn(ih, iw);
            float denom = __fsub_rn(su, inter);
            float iou   = __fdiv_rn(inter, denom);   // IEEE == numpy f32
            if (iou > best) { best = iou; bl = j; }
        }
    }

    if (!valid) return;

    // Matched box: compacted entry, or original box 0 if all IoU == 0
    // (np.argmax of all-zero row -> 0; box 0 may be culled -> global re-read).
    float4 mbx;
    if (bl >= 0) mbx = cbox[bl];           // per-lane ds_read, exec-safe
    else         mbx = bb[0];              // L1/L2-hot, exec-safe
    float mcy = __fmul_rn(__fadd_rn(mbx.x, mbx.z), 0.5f);
    float mcx = __fmul_rn(__fadd_rn(mbx.y, mbx.w), 0.5f);
    float mh  = __fsub_rn(mbx.z, mbx.x);
    float mw  = __fsub_rn(mbx.w, mbx.y);

    size_t o = ((size_t)b * A_TOTAL + a_flat) * 5;
    out[o + 0] = best;
    out[o + 1] = __fmul_rn(__fsub_rn(mcy, cy), inv);
    out[o + 2] = __fmul_rn(__fsub_rn(mcx, cx), inv);
    out[o + 3] = __fmul_rn(__fsub_rn(mh, asize), inv);
    out[o + 4] = __fmul_rn(__fsub_rn(mw, asize), inv);
}

extern "C" void kernel_launch(void* const* d_in, const int* in_sizes, int n_in,
                              void* d_out, int out_size, void* d_ws, size_t ws_size,
                              hipStream_t stream) {
    const float* boxes = (const float*)d_in[0];
    float* out = (float*)d_out;
    dim3 grid(267, 16 /*B*/);
    multi_anchor_encode_v12<<<grid, 128, 0, stream>>>(boxes, out);
}